// Round 9
// baseline (119.431 us; speedup 1.0000x reference)
//
#include <hip/hip_runtime.h>
#include <hip/hip_bf16.h>

static constexpr int EDIM = 128;   // embedding size
static constexpr int FIN  = 256;   // input features

typedef __attribute__((ext_vector_type(8))) short bf16x8;
typedef __attribute__((ext_vector_type(4))) float f32x4;

__device__ inline short f2b(float f) {
    __hip_bfloat16 h = __float2bfloat16(f);
    return *reinterpret_cast<short*>(&h);
}

// ---------------------------------------------------------------------------
// Prep: build FRAGMENT-MAJOR bf16 weights (one bf16x8 per (frag, lane)):
//   WtF[((kt*8+nf)*64+lane)] = A-side-ready B-frag of W   (4096 frags, 64 KB)
//   vwF[((ks*8+nf)*64+lane)] = B-frag of vw^T              (2048 frags, 32 KB)
// plus scalar coefficients and zeroing the CSR 'start' array.
// ---------------------------------------------------------------------------
__global__ __launch_bounds__(256) void k_prep(const float* __restrict__ W,
                                              const float* __restrict__ vw,
                                              const float* __restrict__ lg,
                                              const float* __restrict__ mg,
                                              short* __restrict__ WtF,
                                              short* __restrict__ vwF,
                                              float* __restrict__ sc,
                                              int* __restrict__ start, int M) {
    const int bid = blockIdx.x, tid = threadIdx.x;
    if (bid < 16) {                                // WtF: 4096 fragments
        int idx = bid * 256 + tid;                 // (kt,nf,lane)
        int kt = idx >> 9, rem = idx & 511;
        int nf = rem >> 6, lane = rem & 63;
        int l15 = lane & 15, lhi = lane >> 4;
        bf16x8 fr;
        #pragma unroll
        for (int i = 0; i < 8; ++i)
            fr[i] = f2b(W[(size_t)(kt*32 + lhi*8 + i) * EDIM + nf*16 + l15]);
        *(bf16x8*)(WtF + (size_t)idx * 8) = fr;
    } else if (bid < 24) {                         // vwF: 2048 fragments
        int idx = (bid - 16) * 256 + tid;          // (ks,nf,lane)
        int ks = idx >> 9, rem = idx & 511;
        int nf = rem >> 6, lane = rem & 63;
        int l15 = lane & 15, lhi = lane >> 4;
        bf16x8 fr;
        #pragma unroll
        for (int i = 0; i < 8; ++i)
            fr[i] = f2b(vw[(size_t)(nf*16 + l15) * EDIM + ks*32 + lhi*8 + i]);
        *(bf16x8*)(vwF + (size_t)idx * 8) = fr;
    } else if (bid == 24) {
        if (tid == 0) {
            const float a0 = -1e-9f, a1 = 1.0f + 1e-9f;
            float a_low = 0.f, b_low = 0.f, a_mid = 0.f, c_mid = 0.f;
            for (int i = 0; i < 5; ++i) {
                float l0 = fmaxf(lg[2*i], 0.f), l1 = fmaxf(lg[2*i+1], 0.f);
                a_low += l0 * a0 + l1 * a1;
                b_low += l0 * (1.f - a0) + l1 * (1.f - a1);
                float m0 = fmaxf(mg[2*i], 0.f), m1 = fmaxf(mg[2*i+1], 0.f);
                a_mid += m0 + m1;
                c_mid += m0 * a0 + m1 * a1;
            }
            sc[0] = a_low + a_mid;
            sc[1] = b_low - c_mid;
        }
    } else {
        int i = (bid - 25) * 256 + tid;
        if (i < M) start[i] = 0;
    }
}

// ---------------------------------------------------------------------------
// Mega kernel, 64 KB LDS (2 blocks/CU):
//  blocks [0, gFused): fused MFMA GEMM Y = relu(F@W) @ vw^T. BM=64, 4 waves,
//    wave owns 16 rows. LDS time-multiplexed:
//      phase 1: L[0:32768]  = WtF (staged, frag-major, conflict-free reads)
//      phase 2: L[0:8704]   = Sb transpose slabs (wave-private, aliases WtL)
//               L[8704:25088] = vwF (staged)
//  blocks [gFused, +NCOUNT): XCD-partitioned grid-strided edge count.
// ---------------------------------------------------------------------------
__global__ __launch_bounds__(256) void k_mega(const float* __restrict__ F,
                                              const short* __restrict__ WtF,
                                              const short* __restrict__ vwF,
                                              short* __restrict__ Yb,
                                              const int* __restrict__ ei,
                                              int* __restrict__ start,
                                              int M, int ne, int R, int nCount) {
    __shared__ short L[32768];       // 64 KB
    const int gFused = (M + 63) >> 6;
    const int bid = blockIdx.x, tid = threadIdx.x;

    if (bid >= gFused) {             // ---- grid-strided count path ----
        int bid2 = bid - gFused;
        int part = bid2 & 7;
        int lo = part * R, hi = lo + R;
        int stride = (nCount >> 3) * 256;
        for (int e = (bid2 >> 3) * 256 + tid; e < ne; e += stride) {
            int r = ei[e];
            if (r >= lo && r < hi) atomicAdd(&start[r], 1);
        }
        return;
    }

    // ---- fused GEMM path ----
    const int wave = tid >> 6, lane = tid & 63;
    const int l15  = lane & 15, lhi = lane >> 4;
    const int bm   = bid * 64;
    const int wrow = wave * 16;

    // issue ALL F loads for this lane's A-row upfront (HBM latency first)
    const int gr_a = bm + wrow + l15;
    const bool va  = gr_a < M;
    const float* fp = F + (size_t)(va ? gr_a : 0) * FIN + lhi * 8;
    float4 fa[16];
    #pragma unroll
    for (int t = 0; t < 16; ++t) {
        fa[t] = make_float4(0.f, 0.f, 0.f, 0.f);
        if (va) fa[t] = *(const float4*)(fp + (t >> 1) * 32 + (t & 1) * 4);
    }

    // stage WtF -> L[0:32768] (4096 int4, 16 per thread, linear/coalesced)
    {
        const int4* src = (const int4*)WtF;
        int4* dst = (int4*)L;
        #pragma unroll
        for (int i = 0; i < 16; ++i)
            dst[tid + i * 256] = src[tid + i * 256];
    }
    __syncthreads();

    // GEMM1: sup = relu(F @ W); B-frags = lane-consecutive ds_read_b128
    f32x4 acc[8];
    #pragma unroll
    for (int b = 0; b < 8; ++b) acc[b] = (f32x4){0.f, 0.f, 0.f, 0.f};

    #pragma unroll
    for (int kt = 0; kt < 8; ++kt) {
        float4 a0 = fa[kt*2], a1 = fa[kt*2 + 1];
        bf16x8 af;
        af[0]=f2b(a0.x); af[1]=f2b(a0.y); af[2]=f2b(a0.z); af[3]=f2b(a0.w);
        af[4]=f2b(a1.x); af[5]=f2b(a1.y); af[6]=f2b(a1.z); af[7]=f2b(a1.w);
        #pragma unroll
        for (int nf = 0; nf < 8; ++nf) {
            bf16x8 bf = *(const bf16x8*)(&L[((kt*8 + nf)*64 + lane) * 8]);
            acc[nf] = __builtin_amdgcn_mfma_f32_16x16x32_bf16(af, bf, acc[nf], 0, 0, 0);
        }
    }
    __syncthreads();                 // WtL dead from here; alias region

    // stage vwF -> L[8704:25088] (2048 int4, 8 per thread)
    {
        const int4* src = (const int4*)vwF;
        int4* dst = (int4*)(L + 8704);
        #pragma unroll
        for (int i = 0; i < 8; ++i)
            dst[tid + i * 256] = src[tid + i * 256];
    }
    // relu + bf16 -> Sb slab (wave-private rows in L[0:8704])
    #pragma unroll
    for (int nf = 0; nf < 8; ++nf)
        #pragma unroll
        for (int i = 0; i < 4; ++i)
            L[(wrow + lhi*4 + i) * 136 + nf*16 + l15] = f2b(fmaxf(acc[nf][i], 0.f));
    __syncthreads();                 // vwL staged (Sb is same-wave)

    // GEMM2: Y = sup @ vw^T, all LDS
    f32x4 acc2[8];
    #pragma unroll
    for (int b = 0; b < 8; ++b) acc2[b] = (f32x4){0.f, 0.f, 0.f, 0.f};

    #pragma unroll
    for (int ks = 0; ks < 4; ++ks) {
        bf16x8 af2 = *(const bf16x8*)(&L[(wrow + l15) * 136 + ks*32 + lhi*8]);
        #pragma unroll
        for (int nf = 0; nf < 8; ++nf) {
            bf16x8 bf2 = *(const bf16x8*)(&L[8704 + ((ks*8 + nf)*64 + lane) * 8]);
            acc2[nf] = __builtin_amdgcn_mfma_f32_16x16x32_bf16(af2, bf2, acc2[nf], 0, 0, 0);
        }
    }

    // Y -> slab (own wave's region), then coalesced bf16 store
    #pragma unroll
    for (int nf = 0; nf < 8; ++nf)
        #pragma unroll
        for (int i = 0; i < 4; ++i)
            L[(wrow + lhi*4 + i) * 136 + nf*16 + l15] = f2b(acc2[nf][i]);

    const int srow = lane >> 2;                    // 16 rows, 4 lanes each
    const int sch  = (lane & 3) * 32;              // 64B chunk of the row
    const int gr_s = bm + wrow + srow;
    if (gr_s < M) {
        #pragma unroll
        for (int r = 0; r < 4; ++r) {
            float4 t = *(const float4*)(&L[(wrow + srow) * 136 + sch + r*8]);
            *(float4*)(Yb + (size_t)gr_s * EDIM + sch + r*8) = t;
        }
    }
}

// ---------------------------------------------------------------------------
// Scan (3 small kernels): exclusive prefix sum over per-row counts
// ---------------------------------------------------------------------------
__global__ void k_scan1(const int* __restrict__ cnt, int* __restrict__ bsum, int n) {
    __shared__ int sh[256];
    int t = threadIdx.x;
    int i = blockIdx.x * 256 + t;
    sh[t] = (i < n) ? cnt[i] : 0;
    __syncthreads();
    for (int s = 128; s > 0; s >>= 1) {
        if (t < s) sh[t] += sh[t + s];
        __syncthreads();
    }
    if (t == 0) bsum[blockIdx.x] = sh[0];
}

__global__ void k_scan2(int* __restrict__ bsum, int nb) {
    __shared__ int sh[256];
    int t = threadIdx.x;
    int v = (t < nb) ? bsum[t] : 0;
    sh[t] = v;
    __syncthreads();
    for (int off = 1; off < 256; off <<= 1) {
        int x = (t >= off) ? sh[t - off] : 0;
        __syncthreads();
        sh[t] += x;
        __syncthreads();
    }
    if (t < nb) bsum[t] = sh[t] - v;   // exclusive
}

__global__ void k_scan3(int* __restrict__ start, const int* __restrict__ bsum, int n) {
    __shared__ int sh[256];
    int t = threadIdx.x;
    int i = blockIdx.x * 256 + t;
    int v = (i < n) ? start[i] : 0;
    sh[t] = v;
    __syncthreads();
    for (int off = 1; off < 256; off <<= 1) {
        int x = (t >= off) ? sh[t - off] : 0;
        __syncthreads();
        sh[t] += x;
        __syncthreads();
    }
    if (i < n) start[i] = sh[t] - v + bsum[blockIdx.x];   // exclusive start
}

// ---------------------------------------------------------------------------
// Fill, XCD-partitioned: block (bid&7) handles only rows in its partition so
// each colw/start region is written by one XCD's L2 (no cross-XCD ping-pong).
// ---------------------------------------------------------------------------
__global__ void k_fill(const int* __restrict__ ei, const float* __restrict__ ew,
                       int* __restrict__ start, int2* __restrict__ colw,
                       int ne, int R) {
    int part = blockIdx.x & 7;
    int e = (blockIdx.x >> 3) * 256 + threadIdx.x;
    if (e >= ne) return;
    int r   = ei[e];
    int col = ei[ne + e];
    float w = ew[e];
    int lo = part * R;
    if (r >= lo && r < lo + R) {
        int pos = atomicAdd(&start[r], 1);   // start[r] ends as end-of-row r
        colw[pos] = make_int2(col, __float_as_int(w));
    }
}

// ---------------------------------------------------------------------------
// Fused gather + epilogue: out[row] = Aa * sum_e w_e * Y[col_e] + Bb*Y[row] + 2*vb
// One wave per row; wave-uniform colw loads, 8-way unrolled for MLP.
// ---------------------------------------------------------------------------
__global__ __launch_bounds__(256) void k_gather(const int2* __restrict__ colw,
                                                const int* __restrict__ start,
                                                const __hip_bfloat162* __restrict__ Yb,
                                                const float* __restrict__ vb,
                                                const float* __restrict__ sc,
                                                float* __restrict__ out, int n) {
    int wave = (blockIdx.x * blockDim.x + threadIdx.x) >> 6;
    int lane = threadIdx.x & 63;
    if (wave >= n) return;
    int begin = __builtin_amdgcn_readfirstlane((wave == 0) ? 0 : start[wave - 1]);
    int end   = __builtin_amdgcn_readfirstlane(start[wave]);
    const float Aa = sc[0];
    const float Bb = sc[1];

    float2 acc = make_float2(0.f, 0.f);
    int j = begin;
    for (; j + 8 <= end; j += 8) {
        float2 v[8]; float w[8];
        #pragma unroll
        for (int u = 0; u < 8; ++u) {
            int2 e = colw[j + u];
            w[u] = __int_as_float(e.y);
            v[u] = __bfloat1622float2(Yb[(size_t)e.x * 64 + lane]);
        }
        #pragma unroll
        for (int u = 0; u < 8; ++u) {
            acc.x = fmaf(w[u], v[u].x, acc.x);
            acc.y = fmaf(w[u], v[u].y, acc.y);
        }
    }
    for (; j + 4 <= end; j += 4) {
        float2 v[4]; float w[4];
        #pragma unroll
        for (int u = 0; u < 4; ++u) {
            int2 e = colw[j + u];
            w[u] = __int_as_float(e.y);
            v[u] = __bfloat1622float2(Yb[(size_t)e.x * 64 + lane]);
        }
        #pragma unroll
        for (int u = 0; u < 4; ++u) {
            acc.x = fmaf(w[u], v[u].x, acc.x);
            acc.y = fmaf(w[u], v[u].y, acc.y);
        }
    }
    for (; j < end; ++j) {
        int2 e = colw[j];
        float w = __int_as_float(e.y);
        float2 v = __bfloat1622float2(Yb[(size_t)e.x * 64 + lane]);
        acc.x = fmaf(w, v.x, acc.x);
        acc.y = fmaf(w, v.y, acc.y);
    }
    float2 y = __bfloat1622float2(Yb[(size_t)wave * 64 + lane]);
    float2 b = *(const float2*)(vb + lane * 2);
    float2 o;
    o.x = fmaf(Aa, acc.x, fmaf(Bb, y.x, 2.f * b.x));
    o.y = fmaf(Aa, acc.y, fmaf(Bb, y.y, 2.f * b.y));
    *(float2*)(out + (size_t)wave * EDIM + lane * 2) = o;
}

// ---------------------------------------------------------------------------
extern "C" void kernel_launch(void* const* d_in, const int* in_sizes, int n_in,
                              void* d_out, int out_size, void* d_ws, size_t ws_size,
                              hipStream_t stream) {
    const float* feature = (const float*)d_in[0];
    const int*   eidx    = (const int*)d_in[1];   // [2, NE] int32
    const float* ew      = (const float*)d_in[2];
    const float* weight  = (const float*)d_in[3];
    const float* lg      = (const float*)d_in[4];
    const float* mg      = (const float*)d_in[5];
    // d_in[6..9] = q_w,q_b,k_w,k_b provably unused: softmax over the query axis
    // followed by sum over the query axis makes each k-column of w sum to 1.
    const float* vw      = (const float*)d_in[10];
    const float* vb      = (const float*)d_in[11];
    float* out = (float*)d_out;

    const int M  = in_sizes[0] / FIN;   // 50000
    const int NE = in_sizes[2];         // 600000

    // workspace layout (~18 MB)
    char* ws = (char*)d_ws;
    short* Yb   = (short*)ws;                                   // M*128*2 = 12.8 MB
    char* p = ws + (size_t)M * EDIM * 2;
    int2*  colw = (int2*)p;          p += (size_t)NE * 8;       // 4.8 MB
    int*   start = (int*)p;          p += (size_t)M * 4;        // 200 KB
    int*   bsum = (int*)p;           p += 256 * 4;
    short* WtF  = (short*)p;         p += (size_t)EDIM * FIN * 2;  // 64 KB frag-major
    short* vwF  = (short*)p;         p += (size_t)EDIM * EDIM * 2; // 32 KB frag-major
    float* sc   = (float*)p;

    const int nb = (M + 255) / 256;           // 196 scan blocks (<=256)
    const int R  = (M + 7) / 8;               // rows per XCD partition
    const int NCOUNT = 2048;                  // grid-strided count blocks

    k_prep<<<25 + nb, 256, 0, stream>>>(weight, vw, lg, mg, WtF, vwF, sc, start, M);

    const int gFused = (M + 63) / 64;
    k_mega<<<gFused + NCOUNT, 256, 0, stream>>>(feature, WtF, vwF, Yb,
                                                eidx, start, M, NE, R, NCOUNT);

    k_scan1<<<nb, 256, 0, stream>>>(start, bsum, M);
    k_scan2<<<1, 256, 0, stream>>>(bsum, nb);
    k_scan3<<<nb, 256, 0, stream>>>(start, bsum, M);

    const int gE8 = ((NE + 255) / 256) * 8;
    k_fill<<<gE8, 256, 0, stream>>>(eidx, ew, start, colw, NE, R);

    int gGather = ((M * 64) + 255) / 256;     // one wave per row
    k_gather<<<gGather, 256, 0, stream>>>(colw, start, (const __hip_bfloat162*)Yb,
                                          vb, sc, out, M);
}